// Round 2
// baseline (315.090 us; speedup 1.0000x reference)
//
#include <hip/hip_runtime.h>
#include <stdint.h>

// Problem constants (fixed shapes from setup_inputs)
#define S_LEN  2048
#define B_DIM  8
#define E_DIM  1024
#define BE     (B_DIM * E_DIM)      // 8192  (one time-step's elements)
#define M_ROWS (S_LEN * B_DIM)      // 16384 (GEMM M)
#define NCHUNK 64
#define CLEN   (S_LEN / NCHUNK)     // 32

typedef __attribute__((ext_vector_type(8))) short bf16x8;   // 8 bf16 (4 VGPRs)
typedef __attribute__((ext_vector_type(4))) float f32x4;
typedef __attribute__((ext_vector_type(16))) float f32x16;

__device__ __forceinline__ unsigned short f2bf(float f) {
    // round-to-nearest-even f32 -> bf16 (no NaN inputs expected)
    unsigned int u = __float_as_uint(f);
    u += 0x7FFFu + ((u >> 16) & 1u);
    return (unsigned short)(u >> 16);
}
__device__ __forceinline__ float bf_lo(unsigned int u) {
    return __uint_as_float(u << 16);
}
__device__ __forceinline__ float bf_hi(unsigned int u) {
    return __uint_as_float(u & 0xFFFF0000u);
}

// ---------------------------------------------------------------------------
// 1. token-shift mix: xk = mk*x + (1-mk)*x_prev, xv likewise; output bf16.
// ---------------------------------------------------------------------------
__global__ __launch_bounds__(256) void mix_kernel(
    const float* __restrict__ x, const float* __restrict__ tmrkv,
    unsigned short* __restrict__ xk, unsigned short* __restrict__ xv)
{
    int i = blockIdx.x * 256 + threadIdx.x;           // 8-elem group index
    const float4* x4 = (const float4*)x;
    float4 xc[2], xp[2];
    xc[0] = x4[2 * i];
    xc[1] = x4[2 * i + 1];
    if (i >= BE / 8) {
        xp[0] = x4[2 * i - BE / 4];
        xp[1] = x4[2 * i + 1 - BE / 4];
    } else {
        xp[0] = make_float4(0.f, 0.f, 0.f, 0.f);
        xp[1] = make_float4(0.f, 0.f, 0.f, 0.f);
    }
    int e4 = (2 * i) & (E_DIM / 4 - 1);
    ushort4 ok[2], ov[2];
    #pragma unroll
    for (int h = 0; h < 2; ++h) {
        float4 mk = ((const float4*)(tmrkv + E_DIM))[e4 + h];
        float4 mv = ((const float4*)(tmrkv + 2 * E_DIM))[e4 + h];
        ok[h].x = f2bf(mk.x * xc[h].x + (1.f - mk.x) * xp[h].x);
        ok[h].y = f2bf(mk.y * xc[h].y + (1.f - mk.y) * xp[h].y);
        ok[h].z = f2bf(mk.z * xc[h].z + (1.f - mk.z) * xp[h].z);
        ok[h].w = f2bf(mk.w * xc[h].w + (1.f - mk.w) * xp[h].w);
        ov[h].x = f2bf(mv.x * xc[h].x + (1.f - mv.x) * xp[h].x);
        ov[h].y = f2bf(mv.y * xc[h].y + (1.f - mv.y) * xp[h].y);
        ov[h].z = f2bf(mv.z * xc[h].z + (1.f - mv.z) * xp[h].z);
        ov[h].w = f2bf(mv.w * xc[h].w + (1.f - mv.w) * xp[h].w);
    }
    ((ushort4*)xk)[2 * i]     = ok[0];
    ((ushort4*)xk)[2 * i + 1] = ok[1];
    ((ushort4*)xv)[2 * i]     = ov[0];
    ((ushort4*)xv)[2 * i + 1] = ov[1];
}

// ---------------------------------------------------------------------------
// 2. cast + transpose weights f32[K][N] -> bf16[N][K]; 3 matrices via grid z
// ---------------------------------------------------------------------------
__global__ __launch_bounds__(256) void cast_transpose_k(
    const float* __restrict__ w0, const float* __restrict__ w1,
    const float* __restrict__ w2,
    unsigned short* __restrict__ o0, unsigned short* __restrict__ o1,
    unsigned short* __restrict__ o2)
{
    const float* in = blockIdx.z == 0 ? w0 : (blockIdx.z == 1 ? w1 : w2);
    unsigned short* out = blockIdx.z == 0 ? o0 : (blockIdx.z == 1 ? o1 : o2);
    __shared__ float tile[32][33];
    int bx = blockIdx.x * 32, by = blockIdx.y * 32;
    int tx = threadIdx.x, ty = threadIdx.y;           // block (32, 8)
    #pragma unroll
    for (int i = 0; i < 32; i += 8)
        tile[ty + i][tx] = in[(size_t)(by + ty + i) * E_DIM + bx + tx];
    __syncthreads();
    #pragma unroll
    for (int i = 0; i < 32; i += 8)
        out[(size_t)(bx + ty + i) * E_DIM + by + tx] = f2bf(tile[tx][ty + i]);
}

// ---------------------------------------------------------------------------
// 3. bf16 MFMA GEMM, 256x256 tile, BK=64, 512 threads (8 waves, 2Mx4N),
//    v_mfma_f32_32x32x16_bf16 (2495 TF ceiling vs 2075 for 16x16x32),
//    4 phases / 2 gates per K-tile, counted vmcnt (T3+T4), setprio (T5),
//    XCD-aware block swizzle (T1).
//
//    LDS: 2 buffers x 4 planes of 16 KiB. Plane = [256 rows][32 k] bf16:
//      plane 0 = A k-half0, 1 = B k-half0, 2 = A k-half1, 3 = B k-half1.
//    Stage unit = 1 plane = 2 global_load_lds(16B)/thread, linear LDS dest.
//    Chunk swizzle (both sides): stored chunk c' holds global chunk
//    g = c' ^ ((row>>1)&3). 32x32 frag read (row=lane&31, chunk=s*2+(lane>>5))
//    spreads 8 accesses per 4-bank group = 8 bank-cycles = conflict-free.
//
//    Schedule per tile t (planes of t+1 staged one per phase):
//      GATE(4)  // A0,B0(t) landed (in-order vmcnt: leaves A1,B1(t) in flight)
//      P1: read A-h0(mh0)+B-h0; stage A0(t+1); 8x MFMA
//      P2: read A-h0(mh1);      stage B0(t+1); 8x MFMA (B from regs)
//      GATE(4)  // A1,B1(t) landed (leaves A0,B0(t+1) in flight)
//      P3/P4: mirror for k-half 1
//    Every plane has a 3-phase latency budget; vmcnt never drains in loop.
//    lgkmcnt(0) pinned before each barrier closes the ds_read-vs-DMA race.
// ---------------------------------------------------------------------------
#define BM 256
#define BN 256
#define BK 64

__device__ __forceinline__ void stage_plane(unsigned short* lds_base, int buf_plane,
                                            const unsigned short* gsrc, int K, int wave)
{
    #pragma unroll
    for (int s = 0; s < 2; ++s) {
        const unsigned short* g = gsrc + (size_t)s * 128 * K;   // rows 0..127 / 128..255
        unsigned short* l = lds_base + buf_plane * 8192 + s * 4096 + wave * 512;
        __builtin_amdgcn_global_load_lds(
            (const __attribute__((address_space(1))) unsigned int*)g,
            (__attribute__((address_space(3))) unsigned int*)l, 16, 0, 0);
    }
}

// bijective XCD swizzle: 256 blocks = 8 XCD x 32 CU; each XCD gets 8 x-tiles
// x all 4 y-tiles, all co-resident (1 block/CU) -> A-panels L2-local.
__device__ __forceinline__ void swz_xy(int& bx, int& by)
{
    int hw   = blockIdx.x + gridDim.x * blockIdx.y;   // 0..255 per z-slice
    int xcd  = hw & 7;
    int slot = hw >> 3;                               // 0..31
    bx = xcd * 8 + (slot & 7);                        // 0..63
    by = slot >> 3;                                   // 0..3
}

template <typename OutT>
__device__ __forceinline__ void gemm_body(
    const unsigned short* __restrict__ A,
    const unsigned short* __restrict__ BT,
    OutT* __restrict__ C, int M, int N, int K, int bxt, int byt)
{
    __shared__ __align__(16) unsigned short smem[2][4][8192];   // 128 KiB
    const int tid  = threadIdx.x;                 // 0..511
    const int wave = tid >> 6, lane = tid & 63;
    const int l31 = lane & 31, lh = lane >> 5;    // frag row, frag k-half
    const int wm = wave >> 2, wn = wave & 3;      // wave grid 2(M) x 4(N)
    const int bm = bxt * BM, bn = byt * BN;

    // staging source: thread owns LDS chunk idx = s*512 + tid within a plane;
    // row = idx>>2, stored chunk c' = idx&3 holds global chunk g = c'^((row>>1)&3)
    const int srow = tid >> 2;                    // 0..127 (s adds 128)
    const int sg   = (tid & 3) ^ ((srow >> 1) & 3);
    const unsigned short* sAp = A  + (size_t)(bm + srow) * K + sg * 8;
    const unsigned short* sBp = BT + (size_t)(bn + srow) * K + sg * 8;
    unsigned short* lb = &smem[0][0][0];

    f32x16 acc[4][2];
    #pragma unroll
    for (int i = 0; i < 4; ++i)
        #pragma unroll
        for (int j = 0; j < 2; ++j)
            #pragma unroll
            for (int e = 0; e < 16; ++e)
                acc[i][j][e] = 0.f;

    bf16x8 af[2][2], bfr[2][2];                   // [frag][kstep]

#define GATE_(n)                                                              \
    asm volatile("s_waitcnt lgkmcnt(0)" ::: "memory");                        \
    asm volatile("s_waitcnt vmcnt(" #n ")" ::: "memory");                     \
    __builtin_amdgcn_s_barrier();                                             \
    asm volatile("" ::: "memory");

#define LDA2_(h, mh)                                                          \
    _Pragma("unroll")                                                         \
    for (int ii = 0; ii < 2; ++ii)                                            \
        _Pragma("unroll")                                                     \
        for (int s = 0; s < 2; ++s) {                                         \
            int R = wm * 128 + (2 * (mh) + ii) * 32 + l31;                    \
            int g = s * 2 + lh;                                               \
            af[ii][s] = *(const bf16x8*)&smem[cur][(h) * 2]                   \
                [R * 32 + ((g ^ ((R >> 1) & 3)) << 3)];                       \
        }
#define LDB2_(h)                                                              \
    _Pragma("unroll")                                                         \
    for (int jj = 0; jj < 2; ++jj)                                            \
        _Pragma("unroll")                                                     \
        for (int s = 0; s < 2; ++s) {                                         \
            int R = wn * 64 + jj * 32 + l31;                                  \
            int g = s * 2 + lh;                                               \
            bfr[jj][s] = *(const bf16x8*)&smem[cur][(h) * 2 + 1]              \
                [R * 32 + ((g ^ ((R >> 1) & 3)) << 3)];                       \
        }
#define MMA2_(mh)                                                             \
    __builtin_amdgcn_s_setprio(1);                                            \
    _Pragma("unroll")                                                         \
    for (int ii = 0; ii < 2; ++ii)                                            \
        _Pragma("unroll")                                                     \
        for (int jj = 0; jj < 2; ++jj)                                        \
            _Pragma("unroll")                                                 \
            for (int s = 0; s < 2; ++s)                                       \
                acc[2 * (mh) + ii][jj] =                                      \
                    __builtin_amdgcn_mfma_f32_32x32x16_bf16(                  \
                        af[ii][s], bfr[jj][s], acc[2 * (mh) + ii][jj],        \
                        0, 0, 0);                                             \
    __builtin_amdgcn_s_setprio(0);

    const int nk = K / BK;                        // 16
    // prologue: tile 0, all four planes into buffer 0 (8 loads in flight)
    stage_plane(lb, 0, sAp,      K, wave);
    stage_plane(lb, 1, sBp,      K, wave);
    stage_plane(lb, 2, sAp + 32, K, wave);
    stage_plane(lb, 3, sBp + 32, K, wave);

    int cur = 0;
    for (int t = 0; t < nk - 1; ++t) {
        const int nxt = cur ^ 1;
        const unsigned short* nA = sAp + (size_t)(t + 1) * BK;
        const unsigned short* nB = sBp + (size_t)(t + 1) * BK;
        GATE_(4);                                 // planes 0,1 of tile t ready
        // P1: k-half 0, M-frags 0,1
        LDA2_(0, 0); LDB2_(0);
        stage_plane(lb, nxt * 4 + 0, nA, K, wave);
        MMA2_(0);
        // P2: k-half 0, M-frags 2,3 (B from regs)
        LDA2_(0, 1);
        stage_plane(lb, nxt * 4 + 1, nB, K, wave);
        MMA2_(1);
        GATE_(4);                                 // planes 2,3 of tile t ready
        // P3: k-half 1, M-frags 0,1
        LDA2_(1, 0); LDB2_(1);
        stage_plane(lb, nxt * 4 + 2, nA + 32, K, wave);
        MMA2_(0);
        // P4: k-half 1, M-frags 2,3
        LDA2_(1, 1);
        stage_plane(lb, nxt * 4 + 3, nB + 32, K, wave);
        MMA2_(1);
        cur = nxt;
    }
    // ---- last tile (no staging) ----
    GATE_(4);
    LDA2_(0, 0); LDB2_(0);
    MMA2_(0);
    LDA2_(0, 1);
    MMA2_(1);
    GATE_(0);
    LDA2_(1, 0); LDB2_(1);
    MMA2_(0);
    LDA2_(1, 1);
    MMA2_(1);

    // epilogue: 32x32 C/D map: col = lane&31, row = (r&3)+8*(r>>2)+4*(lane>>5)
    #pragma unroll
    for (int i = 0; i < 4; ++i)
        #pragma unroll
        for (int j = 0; j < 2; ++j)
            #pragma unroll
            for (int r = 0; r < 16; ++r) {
                int row = bm + wm * 128 + i * 32 + (r & 3) + 8 * (r >> 2) + 4 * lh;
                int col = bn + wn * 64 + j * 32 + l31;
                if constexpr (sizeof(OutT) == 2)
                    C[(size_t)row * N + col] = f2bf(acc[i][j][r]);
                else
                    C[(size_t)row * N + col] = acc[i][j][r];
            }
#undef GATE_
#undef LDA2_
#undef LDB2_
#undef MMA2_
}

__global__ __launch_bounds__(512, 2) void gemm_kv(
    const unsigned short* __restrict__ A0, const unsigned short* __restrict__ B0,
    unsigned short* __restrict__ C0,
    const unsigned short* __restrict__ A1, const unsigned short* __restrict__ B1,
    unsigned short* __restrict__ C1, int M, int N, int K)
{
    int bx, by;
    swz_xy(bx, by);
    if (blockIdx.z == 0) gemm_body<unsigned short>(A0, B0, C0, M, N, K, bx, by);
    else                 gemm_body<unsigned short>(A1, B1, C1, M, N, K, bx, by);
}

__global__ __launch_bounds__(512, 2) void gemm_out(
    const unsigned short* __restrict__ A, const unsigned short* __restrict__ BT,
    float* __restrict__ C, int M, int N, int K)
{
    int bx, by;
    swz_xy(bx, by);
    gemm_body<float>(A, BT, C, M, N, K, bx, by);
}

// ---------------------------------------------------------------------------
// 4. WKV associative scan, chunked 3-pass. Element: (v,1,w,k); combine:
//    p'=max(p_l+w_r, p_r); a'=a_l*e1+a_r*e2; b'=b_l*e1+b_r*e2
//    k,v stored bf16; each thread handles 4 adjacent channels (uint2 = 8B).
// ---------------------------------------------------------------------------
__device__ __forceinline__ void wkv_step(float& a, float& b, float& p,
                                         float kt, float vt, float w)
{
    float pw = p + w;
    float pn = fmaxf(pw, kt);
    float e1 = __expf(pw - pn), e2 = __expf(kt - pn);
    a = a * e1 + vt * e2;
    b = b * e1 + e2;
    p = pn;
}

#define Q_PER_T (BE / 4)            // 2048 quad-groups per time-step

__global__ __launch_bounds__(256) void scan_pass1(
    const uint2* __restrict__ k4, const uint2* __restrict__ v4,
    const float* __restrict__ tdec,
    float4* __restrict__ sA, float4* __restrict__ sB, float4* __restrict__ sP)
{
    int g = blockIdx.x * 256 + threadIdx.x;    // quad index: c*Q_PER_T + q
    int q = g & (Q_PER_T - 1);
    int c = g >> 11;
    float4 w4 = ((const float4*)tdec)[q & (E_DIM / 4 - 1)];
    size_t idx = (size_t)c * CLEN * Q_PER_T + q;
    uint2 ku = k4[idx], vu = v4[idx];
    float a0 = bf_lo(vu.x), b0 = 1.f, p0 = bf_lo(ku.x);
    float a1 = bf_hi(vu.x), b1 = 1.f, p1 = bf_hi(ku.x);
    float a2 = bf_lo(vu.y), b2 = 1.f, p2 = bf_lo(ku.y);
    float a3 = bf_hi(vu.y), b3 = 1.f, p3 = bf_hi(ku.y);
    for (int j = 1; j < CLEN; ++j) {
        idx += Q_PER_T;
        ku = k4[idx]; vu = v4[idx];
        wkv_step(a0, b0, p0, bf_lo(ku.x), bf_lo(vu.x), w4.x);
        wkv_step(a1, b1, p1, bf_hi(ku.x), bf_hi(vu.x), w4.y);
        wkv_step(a2, b2, p2, bf_lo(ku.y), bf_lo(vu.y), w4.z);
        wkv_step(a3, b3, p3, bf_hi(ku.y), bf_hi(vu.y), w4.w);
    }
    sA[g] = make_float4(a0, a1, a2, a3);
    sB[g] = make_float4(b0, b1, b2, b3);
    sP[g] = make_float4(p0, p1, p2, p3);
}

// Wave-parallel cross-chunk exclusive scan: block = 64 channels x 64 chunks.
__global__ __launch_bounds__(256) void scan_pass2(
    const float* __restrict__ tdec,
    float* __restrict__ sA, float* __restrict__ sB, float* __restrict__ sP)
{
    __shared__ float tA[64 * 65], tB[64 * 65], tP[64 * 65];
    const int t   = threadIdx.x;
    const int ch0 = blockIdx.x * 64;
    const int chl = t & 63;
    const int cq  = t >> 6;                    // 0..3
    #pragma unroll 4
    for (int cc = 0; cc < 16; ++cc) {
        int c = cq * 16 + cc;
        int idx = c * BE + ch0 + chl;
        tA[chl * 65 + c] = sA[idx];
        tB[chl * 65 + c] = sB[idx];
        tP[chl * 65 + c] = sP[idx];
    }
    __syncthreads();
    const int lane = t & 63, wave = t >> 6;
    for (int i = 0; i < 16; ++i) {
        int ch = wave * 16 + i;                // local channel 0..63
        float w = tdec[(ch0 + ch) & (E_DIM - 1)];
        float a = tA[ch * 65 + lane];
        float b = tB[ch * 65 + lane];
        float p = tP[ch * 65 + lane];
        float W = (float)CLEN * w;             // accumulated decay of this span
        #pragma unroll
        for (int d = 1; d < 64; d <<= 1) {
            float a_l = __shfl_up(a, d);
            float b_l = __shfl_up(b, d);
            float p_l = __shfl_up(p, d);
            float W_l = __shfl_up(W, d);
            if (lane >= d) {
                float pw = p_l + W;            // left.p + right.Wacc
                float pn = fmaxf(pw, p);
                float e1 = __expf(pw - pn), e2 = __expf(p - pn);
                a = a_l * e1 + a * e2;
                b = b_l * e1 + b * e2;
                p = pn;
                W = W_l + W;
            }
        }
        // exclusive = inclusive shifted up by one; identity at chunk 0
        float ea = __shfl_up(a, 1);
        float eb = __shfl_up(b, 1);
        float ep = __shfl_up(p, 1);
        if (lane == 0) { ea = 0.f; eb = 0.f; ep = -__builtin_inff(); }
        tA[ch * 65 + lane] = ea;
        tB[ch * 65 + lane] = eb;
        tP[ch * 65 + lane] = ep;
    }
    __syncthreads();
    #pragma unroll 4
    for (int cc = 0; cc < 16; ++cc) {
        int c = cq * 16 + cc;
        int idx = c * BE + ch0 + chl;
        sA[idx] = tA[chl * 65 + c];
        sB[idx] = tB[chl * 65 + c];
        sP[idx] = tP[chl * 65 + c];
    }
}

__global__ __launch_bounds__(256) void scan_pass3(
    const uint2* __restrict__ k4, const uint2* __restrict__ v4,
    const float* __restrict__ tdec, const float* __restrict__ tfir,
    const float4* __restrict__ sA, const float4* __restrict__ sB,
    const float4* __restrict__ sP, uint2* __restrict__ rwkv4)
{
    int g = blockIdx.x * 256 + threadIdx.x;    // quad index
    int q = g & (Q_PER_T - 1);
    int c = g >> 11;
    int e4 = q & (E_DIM / 4 - 1);
    float4 w4 = ((const float4*)tdec)[e4];
    float4 f4 = ((const float4*)tfir)[e4];
    float u0 = f4.x + w4.x, u1 = f4.y + w4.y;
    float u2 = f4.z + w4.z, u3 = f4.w + w4.w;
    float4 av = sA[g], bv = sB[g], pv = sP[g]; // carry-in (excl prefix)
    float a0 = av.x, b0 = bv.x, p0 = pv.x;
    float a1 = av.y, b1 = bv.y, p1 = pv.y;
    float a2 = av.z, b2 = bv.z, p2 = pv.z;
    float a3 = av.w, b3 = bv.w, p3 = pv.w;
    size_t idx = (size_t)c * CLEN * Q_PER_T + q;
    for (int j = 0; j < CLEN; ++j) {
        uint2 ku = k4[idx], vu = v4[idx];
        float kt0 = bf_lo(ku.x), vt0 = bf_lo(vu.x);
        float kt1 = bf_hi(ku.x), vt1 = bf_hi(vu.x);
        float kt2 = bf_lo(ku.y), vt2 = bf_lo(vu.y);
        float kt3 = bf_hi(ku.y), vt3 = bf_hi(vu.y);
        wkv_step(a0, b0, p0, kt0, vt0, w4.x);
        wkv_step(a1, b1, p1, kt1, vt1, w4.y);
        wkv_step(a2, b2, p2, kt2, vt2, w4.z);
        wkv_step(a3, b3, p3, kt3, vt3, w4.w);
        // bonus-mix output: exp_mix_frac(p, k+u+w, a, b, v, 1)
        float kb0 = kt0 + u0, kb1 = kt1 + u1, kb2 = kt2 + u2, kb3 = kt3 + u3;
        float q0 = fmaxf(p0, kb0), q1 = fmaxf(p1, kb1);
        float q2 = fmaxf(p2, kb2), q3 = fmaxf(p3, kb3);
        float g0 = __expf(p0 - q0), h0 = __expf(kb0 - q0);
        float g1 = __expf(p1 - q1), h1 = __expf(kb1 - q1);
        float g2 = __expf(p2 - q2), h2 = __expf(kb2 - q2);
        float g3 = __expf(p3 - q3), h3 = __expf(kb3 - q3);
        float r0 = (a0 * g0 + vt0 * h0) / (b0 * g0 + h0);
        float r1 = (a1 * g1 + vt1 * h1) / (b1 * g1 + h1);
        float r2 = (a2 * g2 + vt2 * h2) / (b2 * g2 + h2);
        float r3 = (a3 * g3 + vt3 * h3) / (b3 * g3 + h3);
        uint2 o;
        o.x = (unsigned int)f2bf(r0) | ((unsigned int)f2bf(r1) << 16);
        o.y = (unsigned int)f2bf(r2) | ((unsigned int)f2bf(r3) << 16);
        rwkv4[idx] = o;
        idx += Q_PER_T;
    }
}

// ---------------------------------------------------------------------------
extern "C" void kernel_launch(void* const* d_in, const int* in_sizes, int n_in,
                              void* d_out, int out_size, void* d_ws, size_t ws_size,
                              hipStream_t stream)
{
    const float* x     = (const float*)d_in[0];
    const float* tmrkv = (const float*)d_in[1];
    const float* Wk    = (const float*)d_in[2];
    const float* Wv    = (const float*)d_in[3];
    const float* tdec  = (const float*)d_in[4];
    const float* tfir  = (const float*)d_in[5];
    const float* Wout  = (const float*)d_in[6];
    float* out = (float*)d_out;

    // workspace layout (all bf16): xk | xv | k | v | WkT | WvT | WoutT
    // reuse: rwkv -> xk space (dead after gemm_kv); scan scratch -> xv space
    char* ws = (char*)d_ws;
    const size_t SZ_BF = (size_t)M_ROWS * E_DIM * 2;   // 32 MiB
    unsigned short* xk   = (unsigned short*)(ws);
    unsigned short* xv   = (unsigned short*)(ws + SZ_BF);
    unsigned short* kbuf = (unsigned short*)(ws + 2 * SZ_BF);
    unsigned short* vbuf = (unsigned short*)(ws + 3 * SZ_BF);
    unsigned short* WkT  = (unsigned short*)(ws + 4 * SZ_BF);
    unsigned short* WvT  = WkT + (size_t)E_DIM * E_DIM;
    unsigned short* WoutT= WvT + (size_t)E_DIM * E_DIM;
    float* sA = (float*)xv;                    // 2 MiB each, xv dead by then
    float* sB = sA + (size_t)NCHUNK * BE;
    float* sP = sB + (size_t)NCHUNK * BE;
    unsigned short* rwkv = xk;                 // xk dead after gemm_kv

    // 1. mix (reads x; writes xk, xv bf16)
    mix_kernel<<<(M_ROWS * E_DIM / 8) / 256, 256, 0, stream>>>(x, tmrkv, xk, xv);

    // 2. weight casts (f32 [K][N] -> bf16 [N][K]), one launch for all three
    dim3 tb(32, 8), tg(E_DIM / 32, E_DIM / 32, 3);
    cast_transpose_k<<<tg, tb, 0, stream>>>(Wk, Wv, Wout, WkT, WvT, WoutT);

    // 3. k = xk @ Wk, v = xv @ Wv in ONE dispatch (bf16 out)
    dim3 gkv(M_ROWS / BM, E_DIM / BN, 2);
    gemm_kv<<<gkv, 512, 0, stream>>>(xk, WkT, kbuf, xv, WvT, vbuf,
                                     M_ROWS, E_DIM, E_DIM);

    // 4. chunked associative scan -> rwkv bf16 (4 channels per thread)
    scan_pass1<<<(NCHUNK * Q_PER_T) / 256, 256, 0, stream>>>(
        (const uint2*)kbuf, (const uint2*)vbuf, tdec,
        (float4*)sA, (float4*)sB, (float4*)sP);
    scan_pass2<<<BE / 64, 256, 0, stream>>>(tdec, sA, sB, sP);
    scan_pass3<<<(NCHUNK * Q_PER_T) / 256, 256, 0, stream>>>(
        (const uint2*)kbuf, (const uint2*)vbuf, tdec, tfir,
        (const float4*)sA, (const float4*)sB, (const float4*)sP,
        (uint2*)rwkv);

    // 5. out = rwkv @ Wout  (f32 out)
    dim3 gg(M_ROWS / BM, E_DIM / BN);
    gemm_out<<<gg, 512, 0, stream>>>(rwkv, WoutT, out, M_ROWS, E_DIM, E_DIM);
}

// Round 3
// 307.355 us; speedup vs baseline: 1.0252x; 1.0252x over previous
//
#include <hip/hip_runtime.h>
#include <stdint.h>

// Problem constants (fixed shapes from setup_inputs)
#define S_LEN  2048
#define B_DIM  8
#define E_DIM  1024
#define BE     (B_DIM * E_DIM)      // 8192  (one time-step's elements)
#define M_ROWS (S_LEN * B_DIM)      // 16384 (GEMM M)
#define NCHUNK 64
#define CLEN   (S_LEN / NCHUNK)     // 32

typedef __attribute__((ext_vector_type(8))) short bf16x8;   // 8 bf16 (4 VGPRs)
typedef __attribute__((ext_vector_type(4))) float f32x4;
typedef __attribute__((ext_vector_type(16))) float f32x16;

__device__ __forceinline__ unsigned short f2bf(float f) {
    // round-to-nearest-even f32 -> bf16 (no NaN inputs expected)
    unsigned int u = __float_as_uint(f);
    u += 0x7FFFu + ((u >> 16) & 1u);
    return (unsigned short)(u >> 16);
}
__device__ __forceinline__ float bf_lo(unsigned int u) {
    return __uint_as_float(u << 16);
}
__device__ __forceinline__ float bf_hi(unsigned int u) {
    return __uint_as_float(u & 0xFFFF0000u);
}

// ---------------------------------------------------------------------------
// 1. token-shift mix: xk = mk*x + (1-mk)*x_prev, xv likewise; output bf16.
// ---------------------------------------------------------------------------
__global__ __launch_bounds__(256) void mix_kernel(
    const float* __restrict__ x, const float* __restrict__ tmrkv,
    unsigned short* __restrict__ xk, unsigned short* __restrict__ xv)
{
    int i = blockIdx.x * 256 + threadIdx.x;           // 8-elem group index
    const float4* x4 = (const float4*)x;
    float4 xc[2], xp[2];
    xc[0] = x4[2 * i];
    xc[1] = x4[2 * i + 1];
    if (i >= BE / 8) {
        xp[0] = x4[2 * i - BE / 4];
        xp[1] = x4[2 * i + 1 - BE / 4];
    } else {
        xp[0] = make_float4(0.f, 0.f, 0.f, 0.f);
        xp[1] = make_float4(0.f, 0.f, 0.f, 0.f);
    }
    int e4 = (2 * i) & (E_DIM / 4 - 1);
    ushort4 ok[2], ov[2];
    #pragma unroll
    for (int h = 0; h < 2; ++h) {
        float4 mk = ((const float4*)(tmrkv + E_DIM))[e4 + h];
        float4 mv = ((const float4*)(tmrkv + 2 * E_DIM))[e4 + h];
        ok[h].x = f2bf(mk.x * xc[h].x + (1.f - mk.x) * xp[h].x);
        ok[h].y = f2bf(mk.y * xc[h].y + (1.f - mk.y) * xp[h].y);
        ok[h].z = f2bf(mk.z * xc[h].z + (1.f - mk.z) * xp[h].z);
        ok[h].w = f2bf(mk.w * xc[h].w + (1.f - mk.w) * xp[h].w);
        ov[h].x = f2bf(mv.x * xc[h].x + (1.f - mv.x) * xp[h].x);
        ov[h].y = f2bf(mv.y * xc[h].y + (1.f - mv.y) * xp[h].y);
        ov[h].z = f2bf(mv.z * xc[h].z + (1.f - mv.z) * xp[h].z);
        ov[h].w = f2bf(mv.w * xc[h].w + (1.f - mv.w) * xp[h].w);
    }
    ((ushort4*)xk)[2 * i]     = ok[0];
    ((ushort4*)xk)[2 * i + 1] = ok[1];
    ((ushort4*)xv)[2 * i]     = ov[0];
    ((ushort4*)xv)[2 * i + 1] = ov[1];
}

// ---------------------------------------------------------------------------
// 2. cast + transpose weights f32[K][N] -> bf16[N][K]; 3 matrices via grid z
// ---------------------------------------------------------------------------
__global__ __launch_bounds__(256) void cast_transpose_k(
    const float* __restrict__ w0, const float* __restrict__ w1,
    const float* __restrict__ w2,
    unsigned short* __restrict__ o0, unsigned short* __restrict__ o1,
    unsigned short* __restrict__ o2)
{
    const float* in = blockIdx.z == 0 ? w0 : (blockIdx.z == 1 ? w1 : w2);
    unsigned short* out = blockIdx.z == 0 ? o0 : (blockIdx.z == 1 ? o1 : o2);
    __shared__ float tile[32][33];
    int bx = blockIdx.x * 32, by = blockIdx.y * 32;
    int tx = threadIdx.x, ty = threadIdx.y;           // block (32, 8)
    #pragma unroll
    for (int i = 0; i < 32; i += 8)
        tile[ty + i][tx] = in[(size_t)(by + ty + i) * E_DIM + bx + tx];
    __syncthreads();
    #pragma unroll
    for (int i = 0; i < 32; i += 8)
        out[(size_t)(bx + ty + i) * E_DIM + by + tx] = f2bf(tile[tx][ty + i]);
}

// ---------------------------------------------------------------------------
// 3. bf16 MFMA GEMM, 256x256 tile, BK=64, 512 threads (8 waves, 2Mx4N),
//    v_mfma_f32_32x32x16_bf16, counted-vmcnt pipeline (T3+T4), setprio (T5),
//    XCD swizzle (T1).
//
//    LDS: 2 buffers x {A,B} whole tiles [256 rows][64 k] bf16 = 128B rows
//    (full 32-bank span). Chunk swizzle: 8 chunks of 16B per row; stored
//    chunk c' holds global chunk g = c' ^ (row&7) (the round-1/m201-verified
//    conflict-free pattern: every 8-lane group of a frag read covers all 8
//    bank-quads exactly once).  64B-row planes (round 2) measured exactly
//    +4 conflict-cycles per ds_read_b128 -- reverted.
//
//    Schedule per tile t:
//      GATE1: lgkmcnt(0); barrier       // closes ALL reads of tile t-1
//      stage A(t+1), B(t+1) -> nxt      // 8 x global_load_lds(16B)
//      GATE2: vmcnt(8); barrier         // A(t),B(t) landed (in-order retire:
//                                       // 8 newest = t+1's loads, in flight)
//      4 read+MMA phases on tile t (32 MFMA), setprio-wrapped
//    vmcnt never drains in the loop; staged tiles get ~1 K-iter of latency.
//    Write-safety: reads of a buffer finish before GATE1 (lgkmcnt(0)+bar);
//    the overwriting DMA is issued strictly after that barrier.
// ---------------------------------------------------------------------------
#define BM 256
#define BN 256
#define BK 64

__device__ __forceinline__ void stage_tile(unsigned short* lds_plane,
                                           const unsigned short* gsrc,
                                           int K, int wave)
{
    // whole [256][64] bf16 tile: 2048 16B-chunks, 4 loads/thread (s = row>>6)
    #pragma unroll
    for (int s = 0; s < 4; ++s) {
        const unsigned short* g = gsrc + (size_t)s * 64 * K;
        unsigned short* l = lds_plane + s * 4096 + wave * 512;  // + lane*16B (HW)
        __builtin_amdgcn_global_load_lds(
            (const __attribute__((address_space(1))) unsigned int*)g,
            (__attribute__((address_space(3))) unsigned int*)l, 16, 0, 0);
    }
}

// bijective XCD swizzle: 256 blocks = 8 XCD x 32 CU; each XCD gets 8 x-tiles
// x all 4 y-tiles, all co-resident (1 block/CU) -> A-panels L2-local.
__device__ __forceinline__ void swz_xy(int& bx, int& by)
{
    int hw   = blockIdx.x + gridDim.x * blockIdx.y;   // 0..255 per z-slice
    int xcd  = hw & 7;
    int slot = hw >> 3;                               // 0..31
    bx = xcd * 8 + (slot & 7);                        // 0..63
    by = slot >> 3;                                   // 0..3
}

template <typename OutT>
__device__ __forceinline__ void gemm_body(
    const unsigned short* __restrict__ A,
    const unsigned short* __restrict__ BT,
    OutT* __restrict__ C, int M, int N, int K, int bxt, int byt)
{
    __shared__ __align__(16) unsigned short smem[2][2][16384];  // 128 KiB
    const int tid  = threadIdx.x;                 // 0..511
    const int wave = tid >> 6, lane = tid & 63;
    const int l31 = lane & 31, lh = lane >> 5;    // frag row, frag k-sub
    const int wm = wave >> 2, wn = wave & 3;      // wave grid 2(M) x 4(N)
    const int bm = bxt * BM, bn = byt * BN;

    // staging: thread owns chunk idx = s*512 + tid; row = idx>>3 = s*64+(tid>>3),
    // stored chunk c' = tid&7 holds global chunk g = c' ^ (row&7)
    const int srow = tid >> 3;                    // 0..63 (s adds 64)
    const int sg   = (tid & 7) ^ (srow & 7);
    const unsigned short* sAp = A  + (size_t)(bm + srow) * K + sg * 8;
    const unsigned short* sBp = BT + (size_t)(bn + srow) * K + sg * 8;

    f32x16 acc[4][2];
    #pragma unroll
    for (int i = 0; i < 4; ++i)
        #pragma unroll
        for (int j = 0; j < 2; ++j)
            #pragma unroll
            for (int e = 0; e < 16; ++e)
                acc[i][j][e] = 0.f;

    bf16x8 af[2][2], bfr[2][2];                   // [frag][s]

#define LDA2_(h, mh)                                                          \
    _Pragma("unroll")                                                         \
    for (int ii = 0; ii < 2; ++ii)                                            \
        _Pragma("unroll")                                                     \
        for (int s = 0; s < 2; ++s) {                                         \
            int R = wm * 128 + (2 * (mh) + ii) * 32 + l31;                    \
            int c = (h) * 4 + s * 2 + lh;                                     \
            af[ii][s] = *(const bf16x8*)&smem[cur][0]                         \
                [R * 64 + ((c ^ (R & 7)) << 3)];                              \
        }
#define LDB2_(h)                                                              \
    _Pragma("unroll")                                                         \
    for (int jj = 0; jj < 2; ++jj)                                            \
        _Pragma("unroll")                                                     \
        for (int s = 0; s < 2; ++s) {                                         \
            int R = wn * 64 + jj * 32 + l31;                                  \
            int c = (h) * 4 + s * 2 + lh;                                     \
            bfr[jj][s] = *(const bf16x8*)&smem[cur][1]                        \
                [R * 64 + ((c ^ (R & 7)) << 3)];                              \
        }
#define MMA2_(mh)                                                             \
    __builtin_amdgcn_s_setprio(1);                                            \
    _Pragma("unroll")                                                         \
    for (int ii = 0; ii < 2; ++ii)                                            \
        _Pragma("unroll")                                                     \
        for (int jj = 0; jj < 2; ++jj)                                        \
            _Pragma("unroll")                                                 \
            for (int s = 0; s < 2; ++s)                                       \
                acc[2 * (mh) + ii][jj] =                                      \
                    __builtin_amdgcn_mfma_f32_32x32x16_bf16(                  \
                        af[ii][s], bfr[jj][s], acc[2 * (mh) + ii][jj],        \
                        0, 0, 0);                                             \
    __builtin_amdgcn_s_setprio(0);
#define COMPUTE_()                                                            \
    LDB2_(0); LDA2_(0, 0); MMA2_(0);                                          \
    LDA2_(0, 1);           MMA2_(1);                                          \
    LDB2_(1); LDA2_(1, 0); MMA2_(0);                                          \
    LDA2_(1, 1);           MMA2_(1);

    const int nk = K / BK;                        // 16
    // prologue: tile 0 into buffer 0 (8 loads in flight)
    stage_tile(&smem[0][0][0], sAp, K, wave);
    stage_tile(&smem[0][1][0], sBp, K, wave);

    int cur = 0;
    for (int t = 0; t < nk - 1; ++t) {
        const int nxt = cur ^ 1;
        // GATE1: all reads of tile t-1 (this buffer-pair's prev user) done
        asm volatile("s_waitcnt lgkmcnt(0)" ::: "memory");
        __builtin_amdgcn_s_barrier();
        asm volatile("" ::: "memory");
        stage_tile(&smem[nxt][0][0], sAp + (size_t)(t + 1) * BK, K, wave);
        stage_tile(&smem[nxt][1][0], sBp + (size_t)(t + 1) * BK, K, wave);
        // GATE2: tile t landed; tile t+1's 8 loads stay in flight
        asm volatile("s_waitcnt vmcnt(8)" ::: "memory");
        __builtin_amdgcn_s_barrier();
        asm volatile("" ::: "memory");
        COMPUTE_();
        cur = nxt;
    }
    // ---- last tile (no staging; drain is fine here) ----
    asm volatile("s_waitcnt lgkmcnt(0)" ::: "memory");
    __builtin_amdgcn_s_barrier();
    asm volatile("s_waitcnt vmcnt(0)" ::: "memory");
    __builtin_amdgcn_s_barrier();
    asm volatile("" ::: "memory");
    COMPUTE_();

    // epilogue: 32x32 C/D map: col = lane&31, row = (r&3)+8*(r>>2)+4*(lane>>5)
    #pragma unroll
    for (int i = 0; i < 4; ++i)
        #pragma unroll
        for (int j = 0; j < 2; ++j)
            #pragma unroll
            for (int r = 0; r < 16; ++r) {
                int row = bm + wm * 128 + i * 32 + (r & 3) + 8 * (r >> 2) + 4 * lh;
                int col = bn + wn * 64 + j * 32 + l31;
                if constexpr (sizeof(OutT) == 2)
                    C[(size_t)row * N + col] = f2bf(acc[i][j][r]);
                else
                    C[(size_t)row * N + col] = acc[i][j][r];
            }
#undef LDA2_
#undef LDB2_
#undef MMA2_
#undef COMPUTE_
}

__global__ __launch_bounds__(512, 2) void gemm_kv(
    const unsigned short* __restrict__ A0, const unsigned short* __restrict__ B0,
    unsigned short* __restrict__ C0,
    const unsigned short* __restrict__ A1, const unsigned short* __restrict__ B1,
    unsigned short* __restrict__ C1, int M, int N, int K)
{
    int bx, by;
    swz_xy(bx, by);
    if (blockIdx.z == 0) gemm_body<unsigned short>(A0, B0, C0, M, N, K, bx, by);
    else                 gemm_body<unsigned short>(A1, B1, C1, M, N, K, bx, by);
}

__global__ __launch_bounds__(512, 2) void gemm_out(
    const unsigned short* __restrict__ A, const unsigned short* __restrict__ BT,
    float* __restrict__ C, int M, int N, int K)
{
    int bx, by;
    swz_xy(bx, by);
    gemm_body<float>(A, BT, C, M, N, K, bx, by);
}

// ---------------------------------------------------------------------------
// 4. WKV associative scan, chunked 3-pass. Element: (v,1,w,k); combine:
//    p'=max(p_l+w_r, p_r); a'=a_l*e1+a_r*e2; b'=b_l*e1+b_r*e2
//    k,v stored bf16; each thread handles 4 adjacent channels (uint2 = 8B).
// ---------------------------------------------------------------------------
__device__ __forceinline__ void wkv_step(float& a, float& b, float& p,
                                         float kt, float vt, float w)
{
    float pw = p + w;
    float pn = fmaxf(pw, kt);
    float e1 = __expf(pw - pn), e2 = __expf(kt - pn);
    a = a * e1 + vt * e2;
    b = b * e1 + e2;
    p = pn;
}

#define Q_PER_T (BE / 4)            // 2048 quad-groups per time-step

__global__ __launch_bounds__(256) void scan_pass1(
    const uint2* __restrict__ k4, const uint2* __restrict__ v4,
    const float* __restrict__ tdec,
    float4* __restrict__ sA, float4* __restrict__ sB, float4* __restrict__ sP)
{
    int g = blockIdx.x * 256 + threadIdx.x;    // quad index: c*Q_PER_T + q
    int q = g & (Q_PER_T - 1);
    int c = g >> 11;
    float4 w4 = ((const float4*)tdec)[q & (E_DIM / 4 - 1)];
    size_t idx = (size_t)c * CLEN * Q_PER_T + q;
    uint2 ku = k4[idx], vu = v4[idx];
    float a0 = bf_lo(vu.x), b0 = 1.f, p0 = bf_lo(ku.x);
    float a1 = bf_hi(vu.x), b1 = 1.f, p1 = bf_hi(ku.x);
    float a2 = bf_lo(vu.y), b2 = 1.f, p2 = bf_lo(ku.y);
    float a3 = bf_hi(vu.y), b3 = 1.f, p3 = bf_hi(ku.y);
    for (int j = 1; j < CLEN; ++j) {
        idx += Q_PER_T;
        ku = k4[idx]; vu = v4[idx];
        wkv_step(a0, b0, p0, bf_lo(ku.x), bf_lo(vu.x), w4.x);
        wkv_step(a1, b1, p1, bf_hi(ku.x), bf_hi(vu.x), w4.y);
        wkv_step(a2, b2, p2, bf_lo(ku.y), bf_lo(vu.y), w4.z);
        wkv_step(a3, b3, p3, bf_hi(ku.y), bf_hi(vu.y), w4.w);
    }
    sA[g] = make_float4(a0, a1, a2, a3);
    sB[g] = make_float4(b0, b1, b2, b3);
    sP[g] = make_float4(p0, p1, p2, p3);
}

// Wave-parallel cross-chunk exclusive scan: block = 64 channels x 64 chunks.
__global__ __launch_bounds__(256) void scan_pass2(
    const float* __restrict__ tdec,
    float* __restrict__ sA, float* __restrict__ sB, float* __restrict__ sP)
{
    __shared__ float tA[64 * 65], tB[64 * 65], tP[64 * 65];
    const int t   = threadIdx.x;
    const int ch0 = blockIdx.x * 64;
    const int chl = t & 63;
    const int cq  = t >> 6;                    // 0..3
    #pragma unroll 4
    for (int cc = 0; cc < 16; ++cc) {
        int c = cq * 16 + cc;
        int idx = c * BE + ch0 + chl;
        tA[chl * 65 + c] = sA[idx];
        tB[chl * 65 + c] = sB[idx];
        tP[chl * 65 + c] = sP[idx];
    }
    __syncthreads();
    const int lane = t & 63, wave = t >> 6;
    for (int i = 0; i < 16; ++i) {
        int ch = wave * 16 + i;                // local channel 0..63
        float w = tdec[(ch0 + ch) & (E_DIM - 1)];
        float a = tA[ch * 65 + lane];
        float b = tB[ch * 65 + lane];
        float p = tP[ch * 65 + lane];
        float W = (float)CLEN * w;             // accumulated decay of this span
        #pragma unroll
        for (int d = 1; d < 64; d <<= 1) {
            float a_l = __shfl_up(a, d);
            float b_l = __shfl_up(b, d);
            float p_l = __shfl_up(p, d);
            float W_l = __shfl_up(W, d);
            if (lane >= d) {
                float pw = p_l + W;            // left.p + right.Wacc
                float pn = fmaxf(pw, p);
                float e1 = __expf(pw - pn), e2 = __expf(p - pn);
                a = a_l * e1 + a * e2;
                b = b_l * e1 + b * e2;
                p = pn;
                W = W_l + W;
            }
        }
        // exclusive = inclusive shifted up by one; identity at chunk 0
        float ea = __shfl_up(a, 1);
        float eb = __shfl_up(b, 1);
        float ep = __shfl_up(p, 1);
        if (lane == 0) { ea = 0.f; eb = 0.f; ep = -__builtin_inff(); }
        tA[ch * 65 + lane] = ea;
        tB[ch * 65 + lane] = eb;
        tP[ch * 65 + lane] = ep;
    }
    __syncthreads();
    #pragma unroll 4
    for (int cc = 0; cc < 16; ++cc) {
        int c = cq * 16 + cc;
        int idx = c * BE + ch0 + chl;
        sA[idx] = tA[chl * 65 + c];
        sB[idx] = tB[chl * 65 + c];
        sP[idx] = tP[chl * 65 + c];
    }
}

__global__ __launch_bounds__(256) void scan_pass3(
    const uint2* __restrict__ k4, const uint2* __restrict__ v4,
    const float* __restrict__ tdec, const float* __restrict__ tfir,
    const float4* __restrict__ sA, const float4* __restrict__ sB,
    const float4* __restrict__ sP, uint2* __restrict__ rwkv4)
{
    int g = blockIdx.x * 256 + threadIdx.x;    // quad index
    int q = g & (Q_PER_T - 1);
    int c = g >> 11;
    int e4 = q & (E_DIM / 4 - 1);
    float4 w4 = ((const float4*)tdec)[e4];
    float4 f4 = ((const float4*)tfir)[e4];
    float u0 = f4.x + w4.x, u1 = f4.y + w4.y;
    float u2 = f4.z + w4.z, u3 = f4.w + w4.w;
    float4 av = sA[g], bv = sB[g], pv = sP[g]; // carry-in (excl prefix)
    float a0 = av.x, b0 = bv.x, p0 = pv.x;
    float a1 = av.y, b1 = bv.y, p1 = pv.y;
    float a2 = av.z, b2 = bv.z, p2 = pv.z;
    float a3 = av.w, b3 = bv.w, p3 = pv.w;
    size_t idx = (size_t)c * CLEN * Q_PER_T + q;
    for (int j = 0; j < CLEN; ++j) {
        uint2 ku = k4[idx], vu = v4[idx];
        float kt0 = bf_lo(ku.x), vt0 = bf_lo(vu.x);
        float kt1 = bf_hi(ku.x), vt1 = bf_hi(vu.x);
        float kt2 = bf_lo(ku.y), vt2 = bf_lo(vu.y);
        float kt3 = bf_hi(ku.y), vt3 = bf_hi(vu.y);
        wkv_step(a0, b0, p0, kt0, vt0, w4.x);
        wkv_step(a1, b1, p1, kt1, vt1, w4.y);
        wkv_step(a2, b2, p2, kt2, vt2, w4.z);
        wkv_step(a3, b3, p3, kt3, vt3, w4.w);
        // bonus-mix output: exp_mix_frac(p, k+u+w, a, b, v, 1)
        float kb0 = kt0 + u0, kb1 = kt1 + u1, kb2 = kt2 + u2, kb3 = kt3 + u3;
        float q0 = fmaxf(p0, kb0), q1 = fmaxf(p1, kb1);
        float q2 = fmaxf(p2, kb2), q3 = fmaxf(p3, kb3);
        float g0 = __expf(p0 - q0), h0 = __expf(kb0 - q0);
        float g1 = __expf(p1 - q1), h1 = __expf(kb1 - q1);
        float g2 = __expf(p2 - q2), h2 = __expf(kb2 - q2);
        float g3 = __expf(p3 - q3), h3 = __expf(kb3 - q3);
        float r0 = (a0 * g0 + vt0 * h0) / (b0 * g0 + h0);
        float r1 = (a1 * g1 + vt1 * h1) / (b1 * g1 + h1);
        float r2 = (a2 * g2 + vt2 * h2) / (b2 * g2 + h2);
        float r3 = (a3 * g3 + vt3 * h3) / (b3 * g3 + h3);
        uint2 o;
        o.x = (unsigned int)f2bf(r0) | ((unsigned int)f2bf(r1) << 16);
        o.y = (unsigned int)f2bf(r2) | ((unsigned int)f2bf(r3) << 16);
        rwkv4[idx] = o;
        idx += Q_PER_T;
    }
}

// ---------------------------------------------------------------------------
extern "C" void kernel_launch(void* const* d_in, const int* in_sizes, int n_in,
                              void* d_out, int out_size, void* d_ws, size_t ws_size,
                              hipStream_t stream)
{
    const float* x     = (const float*)d_in[0];
    const float* tmrkv = (const float*)d_in[1];
    const float* Wk    = (const float*)d_in[2];
    const float* Wv    = (const float*)d_in[3];
    const float* tdec  = (const float*)d_in[4];
    const float* tfir  = (const float*)d_in[5];
    const float* Wout  = (const float*)d_in[6];
    float* out = (float*)d_out;

    // workspace layout (all bf16): xk | xv | k | v | WkT | WvT | WoutT
    // reuse: rwkv -> xk space (dead after gemm_kv); scan scratch -> xv space
    char* ws = (char*)d_ws;
    const size_t SZ_BF = (size_t)M_ROWS * E_DIM * 2;   // 32 MiB
    unsigned short* xk   = (unsigned short*)(ws);
    unsigned short* xv   = (unsigned short*)(ws + SZ_BF);
    unsigned short* kbuf = (unsigned short*)(ws + 2 * SZ_BF);
    unsigned short* vbuf = (unsigned short*)(ws + 3 * SZ_BF);
    unsigned short* WkT  = (unsigned short*)(ws + 4 * SZ_BF);
    unsigned short* WvT  = WkT + (size_t)E_DIM * E_DIM;
    unsigned short* WoutT= WvT + (size_t)E_DIM * E_DIM;
    float* sA = (float*)xv;                    // 2 MiB each, xv dead by then
    float* sB = sA + (size_t)NCHUNK * BE;
    float* sP = sB + (size_t)NCHUNK * BE;
    unsigned short* rwkv = xk;                 // xk dead after gemm_kv

    // 1. mix (reads x; writes xk, xv bf16)
    mix_kernel<<<(M_ROWS * E_DIM / 8) / 256, 256, 0, stream>>>(x, tmrkv, xk, xv);

    // 2. weight casts (f32 [K][N] -> bf16 [N][K]), one launch for all three
    dim3 tb(32, 8), tg(E_DIM / 32, E_DIM / 32, 3);
    cast_transpose_k<<<tg, tb, 0, stream>>>(Wk, Wv, Wout, WkT, WvT, WoutT);

    // 3. k = xk @ Wk, v = xv @ Wv in ONE dispatch (bf16 out)
    dim3 gkv(M_ROWS / BM, E_DIM / BN, 2);
    gemm_kv<<<gkv, 512, 0, stream>>>(xk, WkT, kbuf, xv, WvT, vbuf,
                                     M_ROWS, E_DIM, E_DIM);

    // 4. chunked associative scan -> rwkv bf16 (4 channels per thread)
    scan_pass1<<<(NCHUNK * Q_PER_T) / 256, 256, 0, stream>>>(
        (const uint2*)kbuf, (const uint2*)vbuf, tdec,
        (float4*)sA, (float4*)sB, (float4*)sP);
    scan_pass2<<<BE / 64, 256, 0, stream>>>(tdec, sA, sB, sP);
    scan_pass3<<<(NCHUNK * Q_PER_T) / 256, 256, 0, stream>>>(
        (const uint2*)kbuf, (const uint2*)vbuf, tdec, tfir,
        (const float4*)sA, (const float4*)sB, (const float4*)sP,
        (uint2*)rwkv);

    // 5. out = rwkv @ Wout  (f32 out)
    dim3 gg(M_ROWS / BM, E_DIM / BN);
    gemm_out<<<gg, 512, 0, stream>>>(rwkv, WoutT, out, M_ROWS, E_DIM, E_DIM);
}